// Round 1
// baseline (249.116 us; speedup 1.0000x reference)
//
#include <hip/hip_runtime.h>
#include <math.h>

#define FDIM 128
#define AVG_D_LOGF 2.6f
#define BN_EPS 1e-5f
#define BM 128
#define BK 64
#define LDK 72   // padded LDS row stride (bf16 elems): 72*2=144B -> 2-way bank alias only

using f32x4 = __attribute__((ext_vector_type(4))) float;
using s16x8 = __attribute__((ext_vector_type(8))) short;
using u16x8 = __attribute__((ext_vector_type(8))) unsigned short;

__device__ __forceinline__ unsigned short f2bf(float x) {
  unsigned int u = __float_as_uint(x);
  u += 0x7FFFu + ((u >> 16) & 1u);   // RNE; inputs are finite
  return (unsigned short)(u >> 16);
}
__device__ __forceinline__ float bf2f(unsigned short u) {
  return __uint_as_float(((unsigned int)u) << 16);
}

// ---------------- CSR build ----------------
__global__ void deg_kernel(const int* __restrict__ dst, int* __restrict__ deg, int E) {
  int i = blockIdx.x * 256 + threadIdx.x;
  if (i < E) atomicAdd(&deg[dst[i]], 1);
}

__global__ void scan1(const int* __restrict__ deg, int* __restrict__ offs,
                      int* __restrict__ bsums, int n) {
  __shared__ int tmp[256];
  int t = threadIdx.x, i = blockIdx.x * 256 + t;
  int v = (i < n) ? deg[i] : 0;
  tmp[t] = v; __syncthreads();
  for (int d = 1; d < 256; d <<= 1) {
    int x = (t >= d) ? tmp[t - d] : 0;
    __syncthreads();
    tmp[t] += x;
    __syncthreads();
  }
  if (i < n) offs[i] = tmp[t] - v;          // block-local exclusive
  if (t == 255) bsums[blockIdx.x] = tmp[255];
}

__global__ void scan2(int* __restrict__ bsums, int nb) {
  __shared__ int tmp[256];
  int t = threadIdx.x;
  int v = (t < nb) ? bsums[t] : 0;
  tmp[t] = v; __syncthreads();
  for (int d = 1; d < 256; d <<= 1) {
    int x = (t >= d) ? tmp[t - d] : 0;
    __syncthreads();
    tmp[t] += x;
    __syncthreads();
  }
  if (t < nb) bsums[t] = tmp[t] - v;        // exclusive block offsets
}

__global__ void scan3(int* __restrict__ offs, const int* __restrict__ bsums, int n, int E) {
  int i = blockIdx.x * 256 + threadIdx.x;
  if (i < n) offs[i] += bsums[blockIdx.x];
  if (i == 0) offs[n] = E;
}

__global__ void csr_fill(const int* __restrict__ src, const int* __restrict__ dst,
                         const int* __restrict__ offs, int* __restrict__ cursor,
                         int* __restrict__ csr, int E) {
  int i = blockIdx.x * 256 + threadIdx.x;
  if (i < E) {
    int d = dst[i];
    int pos = offs[d] + atomicAdd(&cursor[d], 1);
    csr[pos] = src[i];
  }
}

// ---------------- per-node aggregation (one wave per node) ----------------
__global__ __launch_bounds__(256) void agg_kernel(
    const float* __restrict__ h, const int* __restrict__ csr,
    const int* __restrict__ offs, unsigned short* __restrict__ aggb,
    float* __restrict__ s1a, float* __restrict__ s2a, int n) {
  const int gw = (blockIdx.x * 256 + threadIdx.x) >> 6;
  const int lane = threadIdx.x & 63;
  if (gw >= n) return;
  const int beg = offs[gw], end = offs[gw + 1];
  const float2* hp = (const float2*)h;
  float s0 = 0.f, s1 = 0.f, q0 = 0.f, q1 = 0.f;
  float mx0 = -INFINITY, mx1 = -INFINITY, mn0 = INFINITY, mn1 = INFINITY;
  for (int e = beg; e < end; ++e) {
    int sidx = csr[e];
    float2 x = hp[(size_t)sidx * 64 + lane];
    s0 += x.x; s1 += x.y;
    q0 += x.x * x.x; q1 += x.y * x.y;
    mx0 = fmaxf(mx0, x.x); mx1 = fmaxf(mx1, x.y);
    mn0 = fminf(mn0, x.x); mn1 = fminf(mn1, x.y);
  }
  float degf = (float)(end - beg);
  if (degf < 1.f) degf = 1.f;               // every node has a self-loop anyway
  const float inv = 1.f / degf;
  float me0 = s0 * inv, me1 = s1 * inv;
  float v0 = q0 * inv - me0 * me0, v1 = q1 * inv - me1 * me1;
  float st0 = sqrtf(fmaxf(v0, 0.f) + BN_EPS);
  float st1 = sqrtf(fmaxf(v1, 0.f) + BN_EPS);
  unsigned int base = (unsigned int)gw * 512u + (unsigned int)lane * 2u;
  *(unsigned int*)&aggb[base      ] = (unsigned int)f2bf(me0) | ((unsigned int)f2bf(me1) << 16);
  *(unsigned int*)&aggb[base + 128] = (unsigned int)f2bf(mx0) | ((unsigned int)f2bf(mx1) << 16);
  *(unsigned int*)&aggb[base + 256] = (unsigned int)f2bf(mn0) | ((unsigned int)f2bf(mn1) << 16);
  *(unsigned int*)&aggb[base + 384] = (unsigned int)f2bf(st0) | ((unsigned int)f2bf(st1) << 16);
  if (lane == 0) {
    float logd = logf(degf + 1.f);
    s1a[gw] = logd / AVG_D_LOGF;
    s2a[gw] = AVG_D_LOGF / logd;
  }
}

// ---------------- W -> bf16 transposed [FDIM][K] ----------------
__global__ void conv_wt(const float* __restrict__ W, unsigned short* __restrict__ wBT, int K) {
  int idx = blockIdx.x * 256 + threadIdx.x;
  if (idx < K * FDIM) {
    int k = idx >> 7, j = idx & 127;
    wBT[(size_t)j * K + k] = f2bf(W[idx]);
  }
}

// ---------------- fused A-gen GEMM: out = relu(hc @ W + b) ----------------
__global__ __launch_bounds__(256) void gemm_kernel(
    const float* __restrict__ h, const unsigned short* __restrict__ wBT,
    const unsigned short* __restrict__ aggb, const float* __restrict__ s1a,
    const float* __restrict__ s2a, const float* __restrict__ bias,
    float* __restrict__ out, int n, int K) {
  __shared__ unsigned short As[BM * LDK];
  __shared__ unsigned short Bs[FDIM * LDK];
  const int t = threadIdx.x;
  const int lane = t & 63;
  const int w = t >> 6;
  const int wr = w >> 1, wc = w & 1;
  const int m0 = blockIdx.x * BM;

  f32x4 acc[4][4] = {};

  const int r = t >> 1;     // 0..127: A row (node) / B col (j)
  const int half = t & 1;   // k sub-offset 0/32
  int nodeA = m0 + r; if (nodeA >= n) nodeA = n - 1;
  const float sA1 = s1a[nodeA];
  const float sA2 = s2a[nodeA];

  const int nkb = K / BK;   // 26
  for (int kb = 0; kb < nkb; ++kb) {
    const int kg = kb * BK;
    unsigned short* dstA = &As[r * LDK + half * 32];
    if (kg < FDIM) {                                    // h section
      const f32x4* sp = (const f32x4*)(h + (size_t)nodeA * FDIM + kg + half * 32);
      #pragma unroll
      for (int q = 0; q < 4; ++q) {
        f32x4 v0 = sp[2 * q], v1 = sp[2 * q + 1];
        u16x8 o;
        o[0] = f2bf(v0[0]); o[1] = f2bf(v0[1]); o[2] = f2bf(v0[2]); o[3] = f2bf(v0[3]);
        o[4] = f2bf(v1[0]); o[5] = f2bf(v1[1]); o[6] = f2bf(v1[2]); o[7] = f2bf(v1[3]);
        *(u16x8*)(dstA + q * 8) = o;
      }
    } else if (kg < FDIM + 512) {                       // agg (unscaled)
      const u16x8* sp = (const u16x8*)(aggb + (size_t)nodeA * 512 + (kg - FDIM) + half * 32);
      #pragma unroll
      for (int q = 0; q < 4; ++q) *(u16x8*)(dstA + q * 8) = sp[q];
    } else {                                            // agg * s1 or * s2
      const bool is1 = kg < FDIM + 1024;
      const float sc = is1 ? sA1 : sA2;
      const int ko = kg - (is1 ? (FDIM + 512) : (FDIM + 1024));
      const u16x8* sp = (const u16x8*)(aggb + (size_t)nodeA * 512 + ko + half * 32);
      #pragma unroll
      for (int q = 0; q < 4; ++q) {
        u16x8 v = sp[q]; u16x8 o;
        #pragma unroll
        for (int e = 0; e < 8; ++e) o[e] = f2bf(bf2f(v[e]) * sc);
        *(u16x8*)(dstA + q * 8) = o;
      }
    }
    {   // stage B (pre-transposed bf16 W)
      const u16x8* sp = (const u16x8*)(wBT + (size_t)r * K + kg + half * 32);
      unsigned short* dstB = &Bs[r * LDK + half * 32];
      #pragma unroll
      for (int q = 0; q < 4; ++q) *(u16x8*)(dstB + q * 8) = sp[q];
    }
    __syncthreads();
    #pragma unroll
    for (int ks = 0; ks < 2; ++ks) {
      const int lk = ks * 32 + (lane >> 4) * 8;
      const int lr = lane & 15;
      s16x8 a[4], b[4];
      #pragma unroll
      for (int m = 0; m < 4; ++m)
        a[m] = *(const s16x8*)&As[(wr * 64 + m * 16 + lr) * LDK + lk];
      #pragma unroll
      for (int nn = 0; nn < 4; ++nn)
        b[nn] = *(const s16x8*)&Bs[(wc * 64 + nn * 16 + lr) * LDK + lk];
      #pragma unroll
      for (int m = 0; m < 4; ++m)
        #pragma unroll
        for (int nn = 0; nn < 4; ++nn)
          acc[m][nn] = __builtin_amdgcn_mfma_f32_16x16x32_bf16(a[m], b[nn], acc[m][nn], 0, 0, 0);
    }
    __syncthreads();
  }
  // epilogue: +bias, relu, store f32
  #pragma unroll
  for (int m = 0; m < 4; ++m) {
    #pragma unroll
    for (int nn = 0; nn < 4; ++nn) {
      #pragma unroll
      for (int i = 0; i < 4; ++i) {
        int grow = m0 + wr * 64 + m * 16 + (lane >> 4) * 4 + i;
        int gcol = wc * 64 + nn * 16 + (lane & 15);
        if (grow < n) {
          float v = acc[m][nn][i] + bias[gcol];
          out[(size_t)grow * FDIM + gcol] = fmaxf(v, 0.f);
        }
      }
    }
  }
}

// ---------------- BatchNorm (training stats) ----------------
__global__ void bn_reduce(const float* __restrict__ out, float* __restrict__ bnsum,
                          float* __restrict__ bnsq, int n) {
  const int j = threadIdx.x & 127;
  const int rh = threadIdx.x >> 7;
  float s = 0.f, ss = 0.f;
  for (int i = blockIdx.x * 2 + rh; i < n; i += gridDim.x * 2) {
    float x = out[(size_t)i * FDIM + j];
    s += x; ss += x * x;
  }
  __shared__ float red[256];
  red[threadIdx.x] = s; __syncthreads();
  if (rh == 0) { s += red[threadIdx.x + 128]; atomicAdd(&bnsum[j], s); }
  __syncthreads();
  red[threadIdx.x] = ss; __syncthreads();
  if (rh == 0) { ss += red[threadIdx.x + 128]; atomicAdd(&bnsq[j], ss); }
}

__global__ void bn_norm(float* __restrict__ out, const float* __restrict__ bnsum,
                        const float* __restrict__ bnsq, const float* __restrict__ gamma,
                        const float* __restrict__ beta, int n) {
  const int j = threadIdx.x & 127;
  const float invN = 1.f / (float)n;
  const float mu = bnsum[j] * invN;
  const float var = bnsq[j] * invN - mu * mu;
  const float rs = rsqrtf(var + BN_EPS);
  const float sc = gamma[j] * rs;
  const float sh = beta[j] - mu * sc;
  const int gt = blockIdx.x * 256 + threadIdx.x;
  const int row0 = gt >> 7;
  const int rstride = (gridDim.x * 256) >> 7;
  for (int i = row0; i < n; i += rstride) {
    size_t idx = (size_t)i * FDIM + j;
    out[idx] = out[idx] * sc + sh;
  }
}

extern "C" void kernel_launch(void* const* d_in, const int* in_sizes, int n_in,
                              void* d_out, int out_size, void* d_ws, size_t ws_size,
                              hipStream_t stream) {
  const float* h     = (const float*)d_in[0];
  const int*   src   = (const int*)d_in[1];
  const int*   dst   = (const int*)d_in[2];
  const float* W     = (const float*)d_in[3];
  const float* bias  = (const float*)d_in[4];
  const float* gamma = (const float*)d_in[5];
  const float* beta  = (const float*)d_in[6];
  float* out = (float*)d_out;

  const int n = in_sizes[0] / FDIM;      // 50000
  const int E = in_sizes[1];             // 650000
  const int K = in_sizes[3] / FDIM;      // 1664

  char* base = (char*)d_ws;
  size_t off = 0;
  auto alloc = [&](size_t bytes) -> void* {
    void* p = base + off;
    off += (bytes + 255) & ~(size_t)255;
    return p;
  };
  int*   deg    = (int*)  alloc(4ull * n);
  int*   cursor = (int*)  alloc(4ull * n);
  float* bnsum  = (float*)alloc(512);
  float* bnsq   = (float*)alloc(512);
  const size_t zlen = off;               // zero deg+cursor+bn each call
  int*   offs   = (int*)  alloc(4ull * (n + 1));
  int*   bsums  = (int*)  alloc(4ull * 256);
  int*   csr    = (int*)  alloc(4ull * E);
  float* s1a    = (float*)alloc(4ull * n);
  float* s2a    = (float*)alloc(4ull * n);
  unsigned short* aggb = (unsigned short*)alloc(2ull * (size_t)n * 512);
  unsigned short* wBT  = (unsigned short*)alloc(2ull * (size_t)K * FDIM);
  (void)ws_size; (void)n_in; (void)out_size;

  const int eb = (E + 255) / 256;
  const int nb = (n + 255) / 256;

  hipMemsetAsync(d_ws, 0, zlen, stream);
  conv_wt<<<(K * FDIM + 255) / 256, 256, 0, stream>>>(W, wBT, K);
  deg_kernel<<<eb, 256, 0, stream>>>(dst, deg, E);
  scan1<<<nb, 256, 0, stream>>>(deg, offs, bsums, n);
  scan2<<<1, 256, 0, stream>>>(bsums, nb);
  scan3<<<nb, 256, 0, stream>>>(offs, bsums, n, E);
  csr_fill<<<eb, 256, 0, stream>>>(src, dst, offs, cursor, csr, E);
  agg_kernel<<<(n + 3) / 4, 256, 0, stream>>>(h, csr, offs, aggb, s1a, s2a, n);
  gemm_kernel<<<(n + BM - 1) / BM, 256, 0, stream>>>(h, wBT, aggb, s1a, s2a, bias, out, n, K);
  bn_reduce<<<256, 256, 0, stream>>>(out, bnsum, bnsq, n);
  bn_norm<<<1024, 256, 0, stream>>>(out, bnsum, bnsq, gamma, beta, n);
}

// Round 2
// 188.497 us; speedup vs baseline: 1.3216x; 1.3216x over previous
//
#include <hip/hip_runtime.h>
#include <math.h>

#define FDIM 128
#define AVG_D_LOGF 2.6f
#define BN_EPS 1e-5f
#define BM 128
#define BK 64
#define LDK 72   // padded LDS row stride (bf16 elems)

using f32x4 = __attribute__((ext_vector_type(4))) float;
using s16x8 = __attribute__((ext_vector_type(8))) short;
using u16x8 = __attribute__((ext_vector_type(8))) unsigned short;

__device__ __forceinline__ unsigned short f2bf(float x) {
  unsigned int u = __float_as_uint(x);
  u += 0x7FFFu + ((u >> 16) & 1u);   // RNE; inputs are finite
  return (unsigned short)(u >> 16);
}
__device__ __forceinline__ float bf2f(unsigned short u) {
  return __uint_as_float(((unsigned int)u) << 16);
}

// ---------------- h -> bf16 ----------------
__global__ void conv_h(const float* __restrict__ h, unsigned short* __restrict__ hb, int total8) {
  int i = blockIdx.x * 256 + threadIdx.x;
  if (i >= total8) return;
  const f32x4* sp = (const f32x4*)h + (size_t)i * 2;
  f32x4 v0 = sp[0], v1 = sp[1];
  u16x8 o;
  o[0] = f2bf(v0[0]); o[1] = f2bf(v0[1]); o[2] = f2bf(v0[2]); o[3] = f2bf(v0[3]);
  o[4] = f2bf(v1[0]); o[5] = f2bf(v1[1]); o[6] = f2bf(v1[2]); o[7] = f2bf(v1[3]);
  *((u16x8*)hb + i) = o;
}

// ---------------- CSR build ----------------
__global__ void deg_kernel(const int* __restrict__ dst, int* __restrict__ deg, int E) {
  int i = blockIdx.x * 256 + threadIdx.x;
  if (i < E) atomicAdd(&deg[dst[i]], 1);
}

__global__ void scan1(const int* __restrict__ deg, int* __restrict__ offs,
                      int* __restrict__ bsums, int n) {
  __shared__ int tmp[256];
  int t = threadIdx.x, i = blockIdx.x * 256 + t;
  int v = (i < n) ? deg[i] : 0;
  tmp[t] = v; __syncthreads();
  for (int d = 1; d < 256; d <<= 1) {
    int x = (t >= d) ? tmp[t - d] : 0;
    __syncthreads();
    tmp[t] += x;
    __syncthreads();
  }
  if (i < n) offs[i] = tmp[t] - v;
  if (t == 255) bsums[blockIdx.x] = tmp[255];
}

__global__ void scan2(int* __restrict__ bsums, int nb) {
  __shared__ int tmp[256];
  int t = threadIdx.x;
  int v = (t < nb) ? bsums[t] : 0;
  tmp[t] = v; __syncthreads();
  for (int d = 1; d < 256; d <<= 1) {
    int x = (t >= d) ? tmp[t - d] : 0;
    __syncthreads();
    tmp[t] += x;
    __syncthreads();
  }
  if (t < nb) bsums[t] = tmp[t] - v;
}

__global__ void scan3(int* __restrict__ offs, const int* __restrict__ bsums, int n, int E) {
  int i = blockIdx.x * 256 + threadIdx.x;
  if (i < n) offs[i] += bsums[blockIdx.x];
  if (i == 0) offs[n] = E;
}

__global__ void csr_fill(const int* __restrict__ src, const int* __restrict__ dst,
                         const int* __restrict__ offs, int* __restrict__ cursor,
                         int* __restrict__ csr, int E) {
  int i = blockIdx.x * 256 + threadIdx.x;
  if (i < E) {
    int d = dst[i];
    int pos = offs[d] + atomicAdd(&cursor[d], 1);
    csr[pos] = src[i];
  }
}

// ---------------- per-node aggregation (one wave per node, bf16 gather) ----------------
__global__ __launch_bounds__(256) void agg_kernel(
    const unsigned short* __restrict__ hb, const int* __restrict__ csr,
    const int* __restrict__ offs, unsigned short* __restrict__ aggb,
    float* __restrict__ s1a, float* __restrict__ s2a, int n) {
  const int gw = (blockIdx.x * 256 + threadIdx.x) >> 6;
  const int lane = threadIdx.x & 63;
  if (gw >= n) return;
  const int beg = offs[gw], end = offs[gw + 1];
  const unsigned int* hp = (const unsigned int*)hb;    // 2 bf16 per uint, 64 uints/row
  float s0 = 0.f, s1 = 0.f, q0 = 0.f, q1 = 0.f;
  float mx0 = -INFINITY, mx1 = -INFINITY, mn0 = INFINITY, mn1 = INFINITY;
  int e = beg;
  for (; e + 2 <= end; e += 2) {
    int i0 = csr[e], i1 = csr[e + 1];
    unsigned int a = hp[(size_t)i0 * 64 + lane];
    unsigned int b = hp[(size_t)i1 * 64 + lane];
    float a0 = bf2f((unsigned short)(a & 0xFFFFu)), a1 = bf2f((unsigned short)(a >> 16));
    float b0 = bf2f((unsigned short)(b & 0xFFFFu)), b1 = bf2f((unsigned short)(b >> 16));
    s0 += a0 + b0; s1 += a1 + b1;
    q0 += a0 * a0 + b0 * b0; q1 += a1 * a1 + b1 * b1;
    mx0 = fmaxf(mx0, fmaxf(a0, b0)); mx1 = fmaxf(mx1, fmaxf(a1, b1));
    mn0 = fminf(mn0, fminf(a0, b0)); mn1 = fminf(mn1, fminf(a1, b1));
  }
  if (e < end) {
    int i0 = csr[e];
    unsigned int a = hp[(size_t)i0 * 64 + lane];
    float a0 = bf2f((unsigned short)(a & 0xFFFFu)), a1 = bf2f((unsigned short)(a >> 16));
    s0 += a0; s1 += a1;
    q0 += a0 * a0; q1 += a1 * a1;
    mx0 = fmaxf(mx0, a0); mx1 = fmaxf(mx1, a1);
    mn0 = fminf(mn0, a0); mn1 = fminf(mn1, a1);
  }
  float degf = (float)(end - beg);
  if (degf < 1.f) degf = 1.f;
  const float inv = 1.f / degf;
  float me0 = s0 * inv, me1 = s1 * inv;
  float v0 = q0 * inv - me0 * me0, v1 = q1 * inv - me1 * me1;
  float st0 = sqrtf(fmaxf(v0, 0.f) + BN_EPS);
  float st1 = sqrtf(fmaxf(v1, 0.f) + BN_EPS);
  unsigned int base = (unsigned int)gw * 512u + (unsigned int)lane * 2u;
  *(unsigned int*)&aggb[base      ] = (unsigned int)f2bf(me0) | ((unsigned int)f2bf(me1) << 16);
  *(unsigned int*)&aggb[base + 128] = (unsigned int)f2bf(mx0) | ((unsigned int)f2bf(mx1) << 16);
  *(unsigned int*)&aggb[base + 256] = (unsigned int)f2bf(mn0) | ((unsigned int)f2bf(mn1) << 16);
  *(unsigned int*)&aggb[base + 384] = (unsigned int)f2bf(st0) | ((unsigned int)f2bf(st1) << 16);
  if (lane == 0) {
    float logd = logf(degf + 1.f);
    s1a[gw] = logd / AVG_D_LOGF;
    s2a[gw] = AVG_D_LOGF / logd;
  }
}

// ---------------- W -> bf16 transposed [FDIM][K] ----------------
__global__ void conv_wt(const float* __restrict__ W, unsigned short* __restrict__ wBT, int K) {
  int idx = blockIdx.x * 256 + threadIdx.x;
  if (idx < K * FDIM) {
    int k = idx >> 7, j = idx & 127;
    wBT[(size_t)j * K + k] = f2bf(W[idx]);
  }
}

// ---------------- fused GEMM: out = relu(h@W0 + agg@W1 + s1*(agg@W2) + s2*(agg@W3) + b)
// plus fused BN partial column sums.
__global__ __launch_bounds__(256, 2) void gemm_kernel(
    const unsigned short* __restrict__ hb, const unsigned short* __restrict__ wBT,
    const unsigned short* __restrict__ aggb, const float* __restrict__ s1a,
    const float* __restrict__ s2a, const float* __restrict__ bias,
    float* __restrict__ out, float* __restrict__ bnsum, float* __restrict__ bnsq,
    int n, int K) {
  __shared__ unsigned short As[BM * LDK];
  __shared__ unsigned short Bs[3][FDIM * LDK];
  const int t = threadIdx.x;
  const int lane = t & 63;
  const int w = t >> 6;
  const int wr = w >> 1, wc = w & 1;
  const int m0 = blockIdx.x * BM;

  f32x4 acc0[4][4] = {}, acc2[4][4] = {}, acc3[4][4] = {};

  const int r = t >> 1;     // 0..127: A row (node) / B row (out col j)
  const int half = t & 1;   // k sub-offset 0/32
  int nodeA = m0 + r; if (nodeA >= n) nodeA = n - 1;

  const int lk0 = (lane >> 4) * 8;
  const int lr = lane & 15;

  // ---- phase 1: h section (K = 128), B = W rows [0,128) ----
  #pragma unroll
  for (int kb = 0; kb < 2; ++kb) {
    const int kg = kb * BK;
    {
      const u16x8* sp = (const u16x8*)(hb + (size_t)nodeA * FDIM + kg + half * 32);
      unsigned short* dstA = &As[r * LDK + half * 32];
      #pragma unroll
      for (int q = 0; q < 4; ++q) *(u16x8*)(dstA + q * 8) = sp[q];
    }
    {
      const u16x8* sp = (const u16x8*)(wBT + (size_t)r * K + kg + half * 32);
      unsigned short* dstB = &Bs[0][r * LDK + half * 32];
      #pragma unroll
      for (int q = 0; q < 4; ++q) *(u16x8*)(dstB + q * 8) = sp[q];
    }
    __syncthreads();
    #pragma unroll
    for (int ks = 0; ks < 2; ++ks) {
      const int lk = ks * 32 + lk0;
      s16x8 a[4], b[4];
      #pragma unroll
      for (int m = 0; m < 4; ++m)
        a[m] = *(const s16x8*)&As[(wr * 64 + m * 16 + lr) * LDK + lk];
      #pragma unroll
      for (int nn = 0; nn < 4; ++nn)
        b[nn] = *(const s16x8*)&Bs[0][(wc * 64 + nn * 16 + lr) * LDK + lk];
      #pragma unroll
      for (int m = 0; m < 4; ++m)
        #pragma unroll
        for (int nn = 0; nn < 4; ++nn)
          acc0[m][nn] = __builtin_amdgcn_mfma_f32_16x16x32_bf16(a[m], b[nn], acc0[m][nn], 0, 0, 0);
    }
    __syncthreads();
  }

  // ---- phase 2: agg section (K = 512), three B sections ----
  for (int kb = 0; kb < 8; ++kb) {
    const int kg = kb * BK;
    {
      const u16x8* sp = (const u16x8*)(aggb + (size_t)nodeA * 512 + kg + half * 32);
      unsigned short* dstA = &As[r * LDK + half * 32];
      #pragma unroll
      for (int q = 0; q < 4; ++q) *(u16x8*)(dstA + q * 8) = sp[q];
    }
    #pragma unroll
    for (int s = 0; s < 3; ++s) {
      const int woff = FDIM + s * 512 + kg;     // W rows 128 / 640 / 1152 + kg
      const u16x8* sp = (const u16x8*)(wBT + (size_t)r * K + woff + half * 32);
      unsigned short* dstB = &Bs[s][r * LDK + half * 32];
      #pragma unroll
      for (int q = 0; q < 4; ++q) *(u16x8*)(dstB + q * 8) = sp[q];
    }
    __syncthreads();
    #pragma unroll
    for (int ks = 0; ks < 2; ++ks) {
      const int lk = ks * 32 + lk0;
      s16x8 a[4];
      #pragma unroll
      for (int m = 0; m < 4; ++m)
        a[m] = *(const s16x8*)&As[(wr * 64 + m * 16 + lr) * LDK + lk];
      {
        s16x8 b[4];
        #pragma unroll
        for (int nn = 0; nn < 4; ++nn)
          b[nn] = *(const s16x8*)&Bs[0][(wc * 64 + nn * 16 + lr) * LDK + lk];
        #pragma unroll
        for (int m = 0; m < 4; ++m)
          #pragma unroll
          for (int nn = 0; nn < 4; ++nn)
            acc0[m][nn] = __builtin_amdgcn_mfma_f32_16x16x32_bf16(a[m], b[nn], acc0[m][nn], 0, 0, 0);
      }
      {
        s16x8 b[4];
        #pragma unroll
        for (int nn = 0; nn < 4; ++nn)
          b[nn] = *(const s16x8*)&Bs[1][(wc * 64 + nn * 16 + lr) * LDK + lk];
        #pragma unroll
        for (int m = 0; m < 4; ++m)
          #pragma unroll
          for (int nn = 0; nn < 4; ++nn)
            acc2[m][nn] = __builtin_amdgcn_mfma_f32_16x16x32_bf16(a[m], b[nn], acc2[m][nn], 0, 0, 0);
      }
      {
        s16x8 b[4];
        #pragma unroll
        for (int nn = 0; nn < 4; ++nn)
          b[nn] = *(const s16x8*)&Bs[2][(wc * 64 + nn * 16 + lr) * LDK + lk];
        #pragma unroll
        for (int m = 0; m < 4; ++m)
          #pragma unroll
          for (int nn = 0; nn < 4; ++nn)
            acc3[m][nn] = __builtin_amdgcn_mfma_f32_16x16x32_bf16(a[m], b[nn], acc3[m][nn], 0, 0, 0);
      }
    }
    __syncthreads();
  }

  // ---- epilogue: combine, bias, relu, store; per-column BN partial sums ----
  float cs[4] = {0.f, 0.f, 0.f, 0.f}, cq[4] = {0.f, 0.f, 0.f, 0.f};
  #pragma unroll
  for (int m = 0; m < 4; ++m) {
    #pragma unroll
    for (int i = 0; i < 4; ++i) {
      int grow = m0 + wr * 64 + m * 16 + (lane >> 4) * 4 + i;
      if (grow >= n) continue;
      const float sc1 = s1a[grow];
      const float sc2 = s2a[grow];
      #pragma unroll
      for (int nn = 0; nn < 4; ++nn) {
        int gcol = wc * 64 + nn * 16 + (lane & 15);
        float v = acc0[m][nn][i] + sc1 * acc2[m][nn][i] + sc2 * acc3[m][nn][i] + bias[gcol];
        v = fmaxf(v, 0.f);
        out[(size_t)grow * FDIM + gcol] = v;
        cs[nn] += v; cq[nn] += v * v;
      }
    }
  }
  __syncthreads();
  float* red = (float*)As;   // 256 floats: [0,128) col sums, [128,256) col sumsq
  red[t] = 0.f;
  __syncthreads();
  #pragma unroll
  for (int nn = 0; nn < 4; ++nn) {
    int gcol = wc * 64 + nn * 16 + (lane & 15);
    atomicAdd(&red[gcol], cs[nn]);
    atomicAdd(&red[128 + gcol], cq[nn]);
  }
  __syncthreads();
  if (t < 128) atomicAdd(&bnsum[t], red[t]);
  else         atomicAdd(&bnsq[t - 128], red[t]);
}

// ---------------- BatchNorm apply ----------------
__global__ void bn_norm(float* __restrict__ out, const float* __restrict__ bnsum,
                        const float* __restrict__ bnsq, const float* __restrict__ gamma,
                        const float* __restrict__ beta, int n) {
  const int j = threadIdx.x & 127;
  const float invN = 1.f / (float)n;
  const float mu = bnsum[j] * invN;
  const float var = bnsq[j] * invN - mu * mu;
  const float rs = rsqrtf(var + BN_EPS);
  const float sc = gamma[j] * rs;
  const float sh = beta[j] - mu * sc;
  const int gt = blockIdx.x * 256 + threadIdx.x;
  const int row0 = gt >> 7;
  const int rstride = (gridDim.x * 256) >> 7;
  for (int i = row0; i < n; i += rstride) {
    size_t idx = (size_t)i * FDIM + j;
    out[idx] = out[idx] * sc + sh;
  }
}

extern "C" void kernel_launch(void* const* d_in, const int* in_sizes, int n_in,
                              void* d_out, int out_size, void* d_ws, size_t ws_size,
                              hipStream_t stream) {
  const float* h     = (const float*)d_in[0];
  const int*   src   = (const int*)d_in[1];
  const int*   dst   = (const int*)d_in[2];
  const float* W     = (const float*)d_in[3];
  const float* bias  = (const float*)d_in[4];
  const float* gamma = (const float*)d_in[5];
  const float* beta  = (const float*)d_in[6];
  float* out = (float*)d_out;

  const int n = in_sizes[0] / FDIM;      // 50000
  const int E = in_sizes[1];             // 650000
  const int K = in_sizes[3] / FDIM;      // 1664

  char* base = (char*)d_ws;
  size_t off = 0;
  auto alloc = [&](size_t bytes) -> void* {
    void* p = base + off;
    off += (bytes + 255) & ~(size_t)255;
    return p;
  };
  int*   deg    = (int*)  alloc(4ull * n);
  int*   cursor = (int*)  alloc(4ull * n);
  float* bnsum  = (float*)alloc(512);
  float* bnsq   = (float*)alloc(512);
  const size_t zlen = off;               // zero deg+cursor+bn each call
  int*   offs   = (int*)  alloc(4ull * (n + 1));
  int*   bsums  = (int*)  alloc(4ull * 256);
  int*   csr    = (int*)  alloc(4ull * E);
  float* s1a    = (float*)alloc(4ull * n);
  float* s2a    = (float*)alloc(4ull * n);
  unsigned short* aggb = (unsigned short*)alloc(2ull * (size_t)n * 512);
  unsigned short* wBT  = (unsigned short*)alloc(2ull * (size_t)K * FDIM);
  unsigned short* hb   = (unsigned short*)alloc(2ull * (size_t)n * FDIM);
  (void)ws_size; (void)n_in; (void)out_size;

  const int eb = (E + 255) / 256;
  const int nb = (n + 255) / 256;

  hipMemsetAsync(d_ws, 0, zlen, stream);
  conv_h<<<(n * FDIM / 8 + 255) / 256, 256, 0, stream>>>(h, hb, n * FDIM / 8);
  conv_wt<<<(K * FDIM + 255) / 256, 256, 0, stream>>>(W, wBT, K);
  deg_kernel<<<eb, 256, 0, stream>>>(dst, deg, E);
  scan1<<<nb, 256, 0, stream>>>(deg, offs, bsums, n);
  scan2<<<1, 256, 0, stream>>>(bsums, nb);
  scan3<<<nb, 256, 0, stream>>>(offs, bsums, n, E);
  csr_fill<<<eb, 256, 0, stream>>>(src, dst, offs, cursor, csr, E);
  agg_kernel<<<(n + 3) / 4, 256, 0, stream>>>(hb, csr, offs, aggb, s1a, s2a, n);
  gemm_kernel<<<(n + BM - 1) / BM, 256, 0, stream>>>(hb, wBT, aggb, s1a, s2a, bias,
                                                     out, bnsum, bnsq, n, K);
  bn_norm<<<1024, 256, 0, stream>>>(out, bnsum, bnsq, gamma, beta, n);
}

// Round 3
// 179.578 us; speedup vs baseline: 1.3872x; 1.0497x over previous
//
#include <hip/hip_runtime.h>
#include <math.h>

#define FDIM 128
#define AVG_D_LOGF 2.6f
#define BN_EPS 1e-5f
#define NK 10          // K-steps: 2 (h section) + 8 (agg section)

using f32x4 = __attribute__((ext_vector_type(4))) float;
using s16x8 = __attribute__((ext_vector_type(8))) short;
using u16x8 = __attribute__((ext_vector_type(8))) unsigned short;

__device__ __forceinline__ unsigned short f2bf(float x) {
  unsigned int u = __float_as_uint(x);
  u += 0x7FFFu + ((u >> 16) & 1u);   // RNE; inputs are finite
  return (unsigned short)(u >> 16);
}
__device__ __forceinline__ float bf2f(unsigned short u) {
  return __uint_as_float(((unsigned int)u) << 16);
}

__device__ __forceinline__ void gload16(const void* g, void* l) {
  __builtin_amdgcn_global_load_lds(
      (const __attribute__((address_space(1))) void*)g,
      (__attribute__((address_space(3))) void*)l, 16, 0, 0);
}

// ---------------- h -> bf16 ----------------
__global__ void conv_h(const float* __restrict__ h, unsigned short* __restrict__ hb, int total8) {
  int i = blockIdx.x * 256 + threadIdx.x;
  if (i >= total8) return;
  const f32x4* sp = (const f32x4*)h + (size_t)i * 2;
  f32x4 v0 = sp[0], v1 = sp[1];
  u16x8 o;
  o[0] = f2bf(v0[0]); o[1] = f2bf(v0[1]); o[2] = f2bf(v0[2]); o[3] = f2bf(v0[3]);
  o[4] = f2bf(v1[0]); o[5] = f2bf(v1[1]); o[6] = f2bf(v1[2]); o[7] = f2bf(v1[3]);
  *((u16x8*)hb + i) = o;
}

// ---------------- CSR build ----------------
__global__ void deg_kernel(const int* __restrict__ dst, int* __restrict__ deg, int E) {
  int i = blockIdx.x * 256 + threadIdx.x;
  if (i < E) atomicAdd(&deg[dst[i]], 1);
}

__global__ void scan1(const int* __restrict__ deg, int* __restrict__ offs,
                      int* __restrict__ bsums, int n) {
  __shared__ int tmp[256];
  int t = threadIdx.x, i = blockIdx.x * 256 + t;
  int v = (i < n) ? deg[i] : 0;
  tmp[t] = v; __syncthreads();
  for (int d = 1; d < 256; d <<= 1) {
    int x = (t >= d) ? tmp[t - d] : 0;
    __syncthreads();
    tmp[t] += x;
    __syncthreads();
  }
  if (i < n) offs[i] = tmp[t] - v;
  if (t == 255) bsums[blockIdx.x] = tmp[255];
}

__global__ void scan2(int* __restrict__ bsums, int nb) {
  __shared__ int tmp[256];
  int t = threadIdx.x;
  int v = (t < nb) ? bsums[t] : 0;
  tmp[t] = v; __syncthreads();
  for (int d = 1; d < 256; d <<= 1) {
    int x = (t >= d) ? tmp[t - d] : 0;
    __syncthreads();
    tmp[t] += x;
    __syncthreads();
  }
  if (t < nb) bsums[t] = tmp[t] - v;
}

__global__ void scan3(int* __restrict__ offs, const int* __restrict__ bsums, int n, int E) {
  int i = blockIdx.x * 256 + threadIdx.x;
  if (i < n) offs[i] += bsums[blockIdx.x];
  if (i == 0) offs[n] = E;
}

__global__ void csr_fill(const int* __restrict__ src, const int* __restrict__ dst,
                         const int* __restrict__ offs, int* __restrict__ cursor,
                         int* __restrict__ csr, int E) {
  int i = blockIdx.x * 256 + threadIdx.x;
  if (i < E) {
    int d = dst[i];
    int pos = offs[d] + atomicAdd(&cursor[d], 1);
    csr[pos] = src[i];
  }
}

// ---------------- per-node aggregation (one wave per node, bf16 gather) ----------------
__global__ __launch_bounds__(256) void agg_kernel(
    const unsigned short* __restrict__ hb, const int* __restrict__ csr,
    const int* __restrict__ offs, unsigned short* __restrict__ aggb,
    float2* __restrict__ s12a, int n) {
  const int gw = (blockIdx.x * 256 + threadIdx.x) >> 6;
  const int lane = threadIdx.x & 63;
  if (gw >= n) return;
  const int beg = offs[gw], end = offs[gw + 1];
  const unsigned int* hp = (const unsigned int*)hb;    // 2 bf16 per uint, 64 uints/row
  float s0 = 0.f, s1 = 0.f, q0 = 0.f, q1 = 0.f;
  float mx0 = -INFINITY, mx1 = -INFINITY, mn0 = INFINITY, mn1 = INFINITY;
  int e = beg;
  for (; e + 4 <= end; e += 4) {
    int i0 = csr[e], i1 = csr[e + 1], i2 = csr[e + 2], i3 = csr[e + 3];
    unsigned int a = hp[(size_t)i0 * 64 + lane];
    unsigned int b = hp[(size_t)i1 * 64 + lane];
    unsigned int c = hp[(size_t)i2 * 64 + lane];
    unsigned int d = hp[(size_t)i3 * 64 + lane];
    float a0 = bf2f((unsigned short)a), a1 = bf2f((unsigned short)(a >> 16));
    float b0 = bf2f((unsigned short)b), b1 = bf2f((unsigned short)(b >> 16));
    float c0 = bf2f((unsigned short)c), c1 = bf2f((unsigned short)(c >> 16));
    float d0 = bf2f((unsigned short)d), d1 = bf2f((unsigned short)(d >> 16));
    s0 += (a0 + b0) + (c0 + d0); s1 += (a1 + b1) + (c1 + d1);
    q0 += (a0 * a0 + b0 * b0) + (c0 * c0 + d0 * d0);
    q1 += (a1 * a1 + b1 * b1) + (c1 * c1 + d1 * d1);
    mx0 = fmaxf(fmaxf(mx0, a0), fmaxf(b0, fmaxf(c0, d0)));
    mx1 = fmaxf(fmaxf(mx1, a1), fmaxf(b1, fmaxf(c1, d1)));
    mn0 = fminf(fminf(mn0, a0), fminf(b0, fminf(c0, d0)));
    mn1 = fminf(fminf(mn1, a1), fminf(b1, fminf(c1, d1)));
  }
  for (; e < end; ++e) {
    int i0 = csr[e];
    unsigned int a = hp[(size_t)i0 * 64 + lane];
    float a0 = bf2f((unsigned short)a), a1 = bf2f((unsigned short)(a >> 16));
    s0 += a0; s1 += a1;
    q0 += a0 * a0; q1 += a1 * a1;
    mx0 = fmaxf(mx0, a0); mx1 = fmaxf(mx1, a1);
    mn0 = fminf(mn0, a0); mn1 = fminf(mn1, a1);
  }
  float degf = (float)(end - beg);
  if (degf < 1.f) degf = 1.f;
  const float inv = 1.f / degf;
  float me0 = s0 * inv, me1 = s1 * inv;
  float v0 = q0 * inv - me0 * me0, v1 = q1 * inv - me1 * me1;
  float st0 = sqrtf(fmaxf(v0, 0.f) + BN_EPS);
  float st1 = sqrtf(fmaxf(v1, 0.f) + BN_EPS);
  unsigned int base = (unsigned int)gw * 512u + (unsigned int)lane * 2u;
  *(unsigned int*)&aggb[base      ] = (unsigned int)f2bf(me0) | ((unsigned int)f2bf(me1) << 16);
  *(unsigned int*)&aggb[base + 128] = (unsigned int)f2bf(mx0) | ((unsigned int)f2bf(mx1) << 16);
  *(unsigned int*)&aggb[base + 256] = (unsigned int)f2bf(mn0) | ((unsigned int)f2bf(mn1) << 16);
  *(unsigned int*)&aggb[base + 384] = (unsigned int)f2bf(st0) | ((unsigned int)f2bf(st1) << 16);
  if (lane == 0) {
    float logd = logf(degf + 1.f);
    s12a[gw] = make_float2(logd / AVG_D_LOGF, AVG_D_LOGF / logd);
  }
}

// ---------------- W -> bf16 transposed [FDIM][K] ----------------
__global__ void conv_wt(const float* __restrict__ W, unsigned short* __restrict__ wBT, int K) {
  int idx = blockIdx.x * 256 + threadIdx.x;
  if (idx < K * FDIM) {
    int k = idx >> 7, j = idx & 127;
    wBT[(size_t)j * K + k] = f2bf(W[idx]);
  }
}

// ---------------- fused GEMM: out = relu(h@W0 + agg@W1 + s1*(agg@W2) + s2*(agg@W3) + b)
// BM=128, BN=64; dbuf LDS via global_load_lds with source-side XOR swizzle.
__global__ __launch_bounds__(256, 2) void gemm_kernel(
    const unsigned short* __restrict__ hb, const unsigned short* __restrict__ wBT,
    const unsigned short* __restrict__ aggb, const float2* __restrict__ s12a,
    const float* __restrict__ bias, float* __restrict__ out,
    float* __restrict__ bnsum, float* __restrict__ bnsq, int n, int K) {
  __shared__ s16x8 AsB[2][1024];      // 2 x 128 rows x 8 units (16B each) = 32 KB
  __shared__ s16x8 BsB[2][3][512];    // 2 x 3 x 64 rows x 8 units = 48 KB
  const int t = threadIdx.x;
  const int lane = t & 63;
  const int w = t >> 6;
  const int wr = w >> 1, wc = w & 1;
  const int hi = lane >> 4, lr = lane & 15, rx7 = lr & 7;
  const int bx = blockIdx.x;
  const int m0 = (bx >> 1) * 128;
  const int n0 = (bx & 1) * 64;

  f32x4 acc[3][4][2] = {};

  auto stage = [&](int ss, int buf) {
    const bool ph1 = (ss < 2);
    // A tile: 128 rows x 64 cols, 16 gloads (4 per wave)
    #pragma unroll
    for (int i = 0; i < 4; ++i) {
      int unit = w * 256 + i * 64 + lane;
      int row = unit >> 3, x = unit & 7;
      int node = m0 + row; if (node >= n) node = n - 1;
      int xo = (x ^ (row & 7)) << 3;
      const unsigned short* src = ph1
          ? hb   + (size_t)node * FDIM + ss * 64 + xo
          : aggb + (size_t)node * 512 + (ss - 2) * 64 + xo;
      gload16(src, &AsB[buf][w * 256 + i * 64]);
    }
    // B tiles: per section 64 rows x 64 cols, 8 gloads (2 per wave)
    const int nsec = ph1 ? 1 : 3;
    for (int s = 0; s < nsec; ++s) {
      int koff = ph1 ? ss * 64 : (FDIM + s * 512 + (ss - 2) * 64);
      #pragma unroll
      for (int i = 0; i < 2; ++i) {
        int unit = w * 128 + i * 64 + lane;
        int row = unit >> 3, x = unit & 7;
        const unsigned short* src =
            wBT + (size_t)(n0 + row) * K + koff + ((x ^ (row & 7)) << 3);
        gload16(src, &BsB[buf][s][w * 128 + i * 64]);
      }
    }
  };

  stage(0, 0);
  int cur = 0;
  for (int step = 0; step < NK; ++step) {
    if (step + 1 < NK) {
      stage(step + 1, cur ^ 1);
      if (step + 1 < 2) asm volatile("s_waitcnt vmcnt(6)" ::: "memory");
      else              asm volatile("s_waitcnt vmcnt(10)" ::: "memory");
    } else {
      asm volatile("s_waitcnt vmcnt(0)" ::: "memory");
    }
    asm volatile("s_barrier" ::: "memory");
    #pragma unroll
    for (int ks = 0; ks < 2; ++ks) {
      s16x8 a[4];
      #pragma unroll
      for (int m = 0; m < 4; ++m) {
        int row = wr * 64 + m * 16 + lr;
        a[m] = AsB[cur][row * 8 + ((ks * 4 + hi) ^ rx7)];
      }
      #pragma unroll
      for (int s = 0; s < 3; ++s) {
        if (step < 2 && s > 0) continue;    // h section touches only acc[0]
        int rb = wc * 32 + lr;
        s16x8 b0 = BsB[cur][s][rb * 8 + ((ks * 4 + hi) ^ rx7)];
        s16x8 b1 = BsB[cur][s][(rb + 16) * 8 + ((ks * 4 + hi) ^ rx7)];
        #pragma unroll
        for (int m = 0; m < 4; ++m) {
          acc[s][m][0] = __builtin_amdgcn_mfma_f32_16x16x32_bf16(a[m], b0, acc[s][m][0], 0, 0, 0);
          acc[s][m][1] = __builtin_amdgcn_mfma_f32_16x16x32_bf16(a[m], b1, acc[s][m][1], 0, 0, 0);
        }
      }
    }
    asm volatile("s_barrier" ::: "memory");
    cur ^= 1;
  }

  // ---- epilogue: combine, bias, relu, store; fused BN partial sums ----
  float* red = (float*)&AsB[0][0];    // 128 floats
  if (t < 128) red[t] = 0.f;
  __syncthreads();

  const float bv0 = bias[n0 + wc * 32 + lr];
  const float bv1 = bias[n0 + wc * 32 + 16 + lr];
  float cs[2] = {0.f, 0.f}, cq[2] = {0.f, 0.f};
  #pragma unroll
  for (int m = 0; m < 4; ++m) {
    #pragma unroll
    for (int i = 0; i < 4; ++i) {
      int grow = m0 + wr * 64 + m * 16 + hi * 4 + i;
      if (grow >= n) continue;
      float2 sv = s12a[grow];
      #pragma unroll
      for (int nn = 0; nn < 2; ++nn) {
        float v = acc[0][m][nn][i] + sv.x * acc[1][m][nn][i] + sv.y * acc[2][m][nn][i]
                + (nn ? bv1 : bv0);
        v = fmaxf(v, 0.f);
        out[(size_t)grow * FDIM + n0 + wc * 32 + nn * 16 + lr] = v;
        cs[nn] += v; cq[nn] += v * v;
      }
    }
  }
  #pragma unroll
  for (int nn = 0; nn < 2; ++nn) {
    int lc = wc * 32 + nn * 16 + lr;
    atomicAdd(&red[lc], cs[nn]);
    atomicAdd(&red[64 + lc], cq[nn]);
  }
  __syncthreads();
  if (t < 64)       atomicAdd(&bnsum[n0 + t], red[t]);
  else if (t < 128) atomicAdd(&bnsq[n0 + t - 64], red[t]);
}

// ---------------- BatchNorm apply ----------------
__global__ void bn_norm(float* __restrict__ out, const float* __restrict__ bnsum,
                        const float* __restrict__ bnsq, const float* __restrict__ gamma,
                        const float* __restrict__ beta, int n) {
  const int j = threadIdx.x & 127;
  const float invN = 1.f / (float)n;
  const float mu = bnsum[j] * invN;
  const float var = bnsq[j] * invN - mu * mu;
  const float rs = rsqrtf(var + BN_EPS);
  const float sc = gamma[j] * rs;
  const float sh = beta[j] - mu * sc;
  const int gt = blockIdx.x * 256 + threadIdx.x;
  const int row0 = gt >> 7;
  const int rstride = (gridDim.x * 256) >> 7;
  for (int i = row0; i < n; i += rstride) {
    size_t idx = (size_t)i * FDIM + j;
    out[idx] = out[idx] * sc + sh;
  }
}

extern "C" void kernel_launch(void* const* d_in, const int* in_sizes, int n_in,
                              void* d_out, int out_size, void* d_ws, size_t ws_size,
                              hipStream_t stream) {
  const float* h     = (const float*)d_in[0];
  const int*   src   = (const int*)d_in[1];
  const int*   dst   = (const int*)d_in[2];
  const float* W     = (const float*)d_in[3];
  const float* bias  = (const float*)d_in[4];
  const float* gamma = (const float*)d_in[5];
  const float* beta  = (const float*)d_in[6];
  float* out = (float*)d_out;

  const int n = in_sizes[0] / FDIM;      // 50000
  const int E = in_sizes[1];             // 650000
  const int K = in_sizes[3] / FDIM;      // 1664

  char* base = (char*)d_ws;
  size_t off = 0;
  auto alloc = [&](size_t bytes) -> void* {
    void* p = base + off;
    off += (bytes + 255) & ~(size_t)255;
    return p;
  };
  int*   deg    = (int*)  alloc(4ull * n);
  int*   cursor = (int*)  alloc(4ull * n);
  float* bnsum  = (float*)alloc(512);
  float* bnsq   = (float*)alloc(512);
  const size_t zlen = off;               // zero deg+cursor+bn each call
  int*    offs  = (int*)  alloc(4ull * (n + 1));
  int*    bsums = (int*)  alloc(4ull * 256);
  int*    csr   = (int*)  alloc(4ull * E);
  float2* s12a  = (float2*)alloc(8ull * n);
  unsigned short* aggb = (unsigned short*)alloc(2ull * (size_t)n * 512);
  unsigned short* wBT  = (unsigned short*)alloc(2ull * (size_t)K * FDIM);
  unsigned short* hb   = (unsigned short*)alloc(2ull * (size_t)n * FDIM);
  (void)ws_size; (void)n_in; (void)out_size;

  const int eb = (E + 255) / 256;
  const int nb = (n + 255) / 256;

  hipMemsetAsync(d_ws, 0, zlen, stream);
  conv_h<<<(n * FDIM / 8 + 255) / 256, 256, 0, stream>>>(h, hb, n * FDIM / 8);
  conv_wt<<<(K * FDIM + 255) / 256, 256, 0, stream>>>(W, wBT, K);
  deg_kernel<<<eb, 256, 0, stream>>>(dst, deg, E);
  scan1<<<nb, 256, 0, stream>>>(deg, offs, bsums, n);
  scan2<<<1, 256, 0, stream>>>(bsums, nb);
  scan3<<<nb, 256, 0, stream>>>(offs, bsums, n, E);
  csr_fill<<<eb, 256, 0, stream>>>(src, dst, offs, cursor, csr, E);
  agg_kernel<<<(n + 3) / 4, 256, 0, stream>>>(hb, csr, offs, aggb, s12a, n);
  const int gblocks = ((n + 127) / 128) * 2;
  gemm_kernel<<<gblocks, 256, 0, stream>>>(hb, wBT, aggb, s12a, bias,
                                           out, bnsum, bnsq, n, K);
  bn_norm<<<1024, 256, 0, stream>>>(out, bnsum, bnsq, gamma, beta, n);
}

// Round 4
// 175.870 us; speedup vs baseline: 1.4165x; 1.0211x over previous
//
#include <hip/hip_runtime.h>
#include <math.h>

#define FDIM 128
#define AVG_D_LOGF 2.6f
#define BN_EPS 1e-5f
#define NK 10          // K-steps: 2 (h section) + 8 (agg section)

using f32x4 = __attribute__((ext_vector_type(4))) float;
using s16x8 = __attribute__((ext_vector_type(8))) short;
using u16x8 = __attribute__((ext_vector_type(8))) unsigned short;

__device__ __forceinline__ unsigned short f2bf(float x) {
  unsigned int u = __float_as_uint(x);
  u += 0x7FFFu + ((u >> 16) & 1u);   // RNE; inputs are finite
  return (unsigned short)(u >> 16);
}
__device__ __forceinline__ float bf2f(unsigned short u) {
  return __uint_as_float(((unsigned int)u) << 16);
}

__device__ __forceinline__ void gload16(const void* g, void* l) {
  __builtin_amdgcn_global_load_lds(
      (const __attribute__((address_space(1))) void*)g,
      (__attribute__((address_space(3))) void*)l, 16, 0, 0);
}

// ---------------- fused prep: h->bf16, W->bf16 transposed, degree count ----------------
__global__ void prep_kernel(const float* __restrict__ h, unsigned short* __restrict__ hb,
                            const float* __restrict__ W, unsigned short* __restrict__ wBT,
                            const int* __restrict__ dst, int* __restrict__ deg,
                            int w0, int w1, int w2, int K) {
  int i = blockIdx.x * 256 + threadIdx.x;
  if (i < w0) {                       // conv_h: 8 elems per thread
    const f32x4* sp = (const f32x4*)h + (size_t)i * 2;
    f32x4 v0 = sp[0], v1 = sp[1];
    u16x8 o;
    o[0] = f2bf(v0[0]); o[1] = f2bf(v0[1]); o[2] = f2bf(v0[2]); o[3] = f2bf(v0[3]);
    o[4] = f2bf(v1[0]); o[5] = f2bf(v1[1]); o[6] = f2bf(v1[2]); o[7] = f2bf(v1[3]);
    *((u16x8*)hb + i) = o;
  } else if (i < w0 + w1) {           // conv_wt: 1 elem per thread
    int idx = i - w0;
    int k = idx >> 7, j = idx & 127;
    wBT[(size_t)j * K + k] = f2bf(W[idx]);
  } else if (i < w0 + w1 + w2) {      // degree count
    atomicAdd(&deg[dst[i - w0 - w1]], 1);
  }
}

// ---------------- CSR build ----------------
__global__ void scan1(const int* __restrict__ deg, int* __restrict__ offs,
                      int* __restrict__ bsums, int n) {
  __shared__ int tmp[256];
  int t = threadIdx.x, i = blockIdx.x * 256 + t;
  int v = (i < n) ? deg[i] : 0;
  tmp[t] = v; __syncthreads();
  for (int d = 1; d < 256; d <<= 1) {
    int x = (t >= d) ? tmp[t - d] : 0;
    __syncthreads();
    tmp[t] += x;
    __syncthreads();
  }
  if (i < n) offs[i] = tmp[t] - v;
  if (t == 255) bsums[blockIdx.x] = tmp[255];
}

__global__ void scan2(int* __restrict__ bsums, int nb) {
  __shared__ int tmp[256];
  int t = threadIdx.x;
  int v = (t < nb) ? bsums[t] : 0;
  tmp[t] = v; __syncthreads();
  for (int d = 1; d < 256; d <<= 1) {
    int x = (t >= d) ? tmp[t - d] : 0;
    __syncthreads();
    tmp[t] += x;
    __syncthreads();
  }
  if (t < nb) bsums[t] = tmp[t] - v;
}

__global__ void scan3(int* __restrict__ offs, const int* __restrict__ bsums, int n, int E) {
  int i = blockIdx.x * 256 + threadIdx.x;
  if (i < n) offs[i] += bsums[blockIdx.x];
  if (i == 0) offs[n] = E;
}

__global__ void csr_fill(const int* __restrict__ src, const int* __restrict__ dst,
                         const int* __restrict__ offs, int* __restrict__ cursor,
                         int* __restrict__ csr, int E) {
  int i = blockIdx.x * 256 + threadIdx.x;
  if (i < E) {
    int d = dst[i];
    int pos = offs[d] + atomicAdd(&cursor[d], 1);
    csr[pos] = src[i];
  }
}

// ---------------- per-node aggregation (one wave per node, bf16 gather) ----------------
__global__ __launch_bounds__(256) void agg_kernel(
    const unsigned short* __restrict__ hb, const int* __restrict__ csr,
    const int* __restrict__ offs, unsigned short* __restrict__ aggb,
    float2* __restrict__ s12a, int n) {
  const int gw = (blockIdx.x * 256 + threadIdx.x) >> 6;
  const int lane = threadIdx.x & 63;
  if (gw >= n) return;
  const int beg = offs[gw], end = offs[gw + 1];
  const unsigned int* hp = (const unsigned int*)hb;    // 2 bf16 per uint, 64 uints/row
  float s0 = 0.f, s1 = 0.f, q0 = 0.f, q1 = 0.f;
  float mx0 = -INFINITY, mx1 = -INFINITY, mn0 = INFINITY, mn1 = INFINITY;
  int e = beg;
  for (; e + 4 <= end; e += 4) {
    int i0 = csr[e], i1 = csr[e + 1], i2 = csr[e + 2], i3 = csr[e + 3];
    unsigned int a = hp[(size_t)i0 * 64 + lane];
    unsigned int b = hp[(size_t)i1 * 64 + lane];
    unsigned int c = hp[(size_t)i2 * 64 + lane];
    unsigned int d = hp[(size_t)i3 * 64 + lane];
    float a0 = bf2f((unsigned short)a), a1 = bf2f((unsigned short)(a >> 16));
    float b0 = bf2f((unsigned short)b), b1 = bf2f((unsigned short)(b >> 16));
    float c0 = bf2f((unsigned short)c), c1 = bf2f((unsigned short)(c >> 16));
    float d0 = bf2f((unsigned short)d), d1 = bf2f((unsigned short)(d >> 16));
    s0 += (a0 + b0) + (c0 + d0); s1 += (a1 + b1) + (c1 + d1);
    q0 += (a0 * a0 + b0 * b0) + (c0 * c0 + d0 * d0);
    q1 += (a1 * a1 + b1 * b1) + (c1 * c1 + d1 * d1);
    mx0 = fmaxf(fmaxf(mx0, a0), fmaxf(b0, fmaxf(c0, d0)));
    mx1 = fmaxf(fmaxf(mx1, a1), fmaxf(b1, fmaxf(c1, d1)));
    mn0 = fminf(fminf(mn0, a0), fminf(b0, fminf(c0, d0)));
    mn1 = fminf(fminf(mn1, a1), fminf(b1, fminf(c1, d1)));
  }
  for (; e < end; ++e) {
    int i0 = csr[e];
    unsigned int a = hp[(size_t)i0 * 64 + lane];
    float a0 = bf2f((unsigned short)a), a1 = bf2f((unsigned short)(a >> 16));
    s0 += a0; s1 += a1;
    q0 += a0 * a0; q1 += a1 * a1;
    mx0 = fmaxf(mx0, a0); mx1 = fmaxf(mx1, a1);
    mn0 = fminf(mn0, a0); mn1 = fminf(mn1, a1);
  }
  float degf = (float)(end - beg);
  if (degf < 1.f) degf = 1.f;
  const float inv = 1.f / degf;
  float me0 = s0 * inv, me1 = s1 * inv;
  float v0 = q0 * inv - me0 * me0, v1 = q1 * inv - me1 * me1;
  float st0 = sqrtf(fmaxf(v0, 0.f) + BN_EPS);
  float st1 = sqrtf(fmaxf(v1, 0.f) + BN_EPS);
  unsigned int base = (unsigned int)gw * 512u + (unsigned int)lane * 2u;
  *(unsigned int*)&aggb[base      ] = (unsigned int)f2bf(me0) | ((unsigned int)f2bf(me1) << 16);
  *(unsigned int*)&aggb[base + 128] = (unsigned int)f2bf(mx0) | ((unsigned int)f2bf(mx1) << 16);
  *(unsigned int*)&aggb[base + 256] = (unsigned int)f2bf(mn0) | ((unsigned int)f2bf(mn1) << 16);
  *(unsigned int*)&aggb[base + 384] = (unsigned int)f2bf(st0) | ((unsigned int)f2bf(st1) << 16);
  if (lane == 0) {
    float logd = logf(degf + 1.f);
    s12a[gw] = make_float2(logd / AVG_D_LOGF, AVG_D_LOGF / logd);
  }
}

// ---------------- fused GEMM: out = relu(h@W0 + agg@W1 + s1*(agg@W2) + s2*(agg@W3) + b)
// BM=128, BN=64; single-buffer LDS (40 KB) via global_load_lds + source XOR swizzle;
// ~3 blocks/CU co-residency provides the pipeline overlap (m97 structure).
__global__ __launch_bounds__(256, 3) void gemm_kernel(
    const unsigned short* __restrict__ hb, const unsigned short* __restrict__ wBT,
    const unsigned short* __restrict__ aggb, const float2* __restrict__ s12a,
    const float* __restrict__ bias, float* __restrict__ out,
    float* __restrict__ bnsum, float* __restrict__ bnsq, int n, int K) {
  __shared__ s16x8 As[1024];      // 128 rows x 8 units (16B each) = 16 KB
  __shared__ s16x8 Bs[3][512];    // 3 x 64 rows x 8 units = 24 KB
  const int t = threadIdx.x;
  const int lane = t & 63;
  const int w = t >> 6;
  const int wr = w >> 1, wc = w & 1;
  const int hi = lane >> 4, lr = lane & 15, rx7 = lr & 7;

  // bijective XCD-chunked swizzle (m204): co-locate the two N-blocks of each
  // M-tile on one XCD's L2 so A's second read is an L2 hit.
  const int nwg = gridDim.x;
  const int q = nwg >> 3, r = nwg & 7;
  const int xcd = blockIdx.x & 7, jj = blockIdx.x >> 3;
  const int bx = (xcd < r ? xcd * (q + 1) : r * (q + 1) + (xcd - r) * q) + jj;

  const int m0 = (bx >> 1) * 128;
  const int n0 = (bx & 1) * 64;

  f32x4 acc[3][4][2] = {};

  auto stage = [&](int ss) {
    const bool ph1 = (ss < 2);
    // A tile: 128 rows x 64 cols, 16 gloads (4 per wave)
    #pragma unroll
    for (int i = 0; i < 4; ++i) {
      int unit = w * 256 + i * 64 + lane;
      int row = unit >> 3, x = unit & 7;
      int node = m0 + row; if (node >= n) node = n - 1;
      int xo = (x ^ (row & 7)) << 3;
      const unsigned short* src = ph1
          ? hb   + (size_t)node * FDIM + ss * 64 + xo
          : aggb + (size_t)node * 512 + (ss - 2) * 64 + xo;
      gload16(src, &As[w * 256 + i * 64]);
    }
    // B tiles: per section 64 rows x 64 cols, 8 gloads (2 per wave)
    const int nsec = ph1 ? 1 : 3;
    for (int s = 0; s < nsec; ++s) {
      int koff = ph1 ? ss * 64 : (FDIM + s * 512 + (ss - 2) * 64);
      #pragma unroll
      for (int i = 0; i < 2; ++i) {
        int unit = w * 128 + i * 64 + lane;
        int row = unit >> 3, x = unit & 7;
        const unsigned short* src =
            wBT + (size_t)(n0 + row) * K + koff + ((x ^ (row & 7)) << 3);
        gload16(src, &Bs[s][w * 128 + i * 64]);
      }
    }
  };

  for (int step = 0; step < NK; ++step) {
    stage(step);
    __syncthreads();                  // drains vmcnt(0) then barrier
    #pragma unroll
    for (int ks = 0; ks < 2; ++ks) {
      s16x8 a[4];
      #pragma unroll
      for (int m = 0; m < 4; ++m) {
        int row = wr * 64 + m * 16 + lr;
        a[m] = As[row * 8 + ((ks * 4 + hi) ^ rx7)];
      }
      #pragma unroll
      for (int s = 0; s < 3; ++s) {
        if (step < 2 && s > 0) continue;    // h section touches only acc[0]
        int rb = wc * 32 + lr;
        s16x8 b0 = Bs[s][rb * 8 + ((ks * 4 + hi) ^ rx7)];
        s16x8 b1 = Bs[s][(rb + 16) * 8 + ((ks * 4 + hi) ^ rx7)];
        #pragma unroll
        for (int m = 0; m < 4; ++m) {
          acc[s][m][0] = __builtin_amdgcn_mfma_f32_16x16x32_bf16(a[m], b0, acc[s][m][0], 0, 0, 0);
          acc[s][m][1] = __builtin_amdgcn_mfma_f32_16x16x32_bf16(a[m], b1, acc[s][m][1], 0, 0, 0);
        }
      }
    }
    __syncthreads();                  // LDS free before next stage
  }

  // ---- epilogue: combine, bias, relu, store; fused BN partial sums ----
  float* red = (float*)&As[0];        // 128 floats
  if (t < 128) red[t] = 0.f;
  __syncthreads();

  const float bv0 = bias[n0 + wc * 32 + lr];
  const float bv1 = bias[n0 + wc * 32 + 16 + lr];
  float cs[2] = {0.f, 0.f}, cq[2] = {0.f, 0.f};
  #pragma unroll
  for (int m = 0; m < 4; ++m) {
    #pragma unroll
    for (int i = 0; i < 4; ++i) {
      int grow = m0 + wr * 64 + m * 16 + hi * 4 + i;
      if (grow >= n) continue;
      float2 sv = s12a[grow];
      #pragma unroll
      for (int nn = 0; nn < 2; ++nn) {
        float v = acc[0][m][nn][i] + sv.x * acc[1][m][nn][i] + sv.y * acc[2][m][nn][i]
                + (nn ? bv1 : bv0);
        v = fmaxf(v, 0.f);
        out[(size_t)grow * FDIM + n0 + wc * 32 + nn * 16 + lr] = v;
        cs[nn] += v; cq[nn] += v * v;
      }
    }
  }
  #pragma unroll
  for (int nn = 0; nn < 2; ++nn) {
    int lc = wc * 32 + nn * 16 + lr;
    atomicAdd(&red[lc], cs[nn]);
    atomicAdd(&red[64 + lc], cq[nn]);
  }
  __syncthreads();
  if (t < 64)       atomicAdd(&bnsum[n0 + t], red[t]);
  else if (t < 128) atomicAdd(&bnsq[n0 + t - 64], red[t]);
}

// ---------------- BatchNorm apply ----------------
__global__ void bn_norm(float* __restrict__ out, const float* __restrict__ bnsum,
                        const float* __restrict__ bnsq, const float* __restrict__ gamma,
                        const float* __restrict__ beta, int n) {
  const int j = threadIdx.x & 127;
  const float invN = 1.f / (float)n;
  const float mu = bnsum[j] * invN;
  const float var = bnsq[j] * invN - mu * mu;
  const float rs = rsqrtf(var + BN_EPS);
  const float sc = gamma[j] * rs;
  const float sh = beta[j] - mu * sc;
  const int gt = blockIdx.x * 256 + threadIdx.x;
  const int row0 = gt >> 7;
  const int rstride = (gridDim.x * 256) >> 7;
  for (int i = row0; i < n; i += rstride) {
    size_t idx = (size_t)i * FDIM + j;
    out[idx] = out[idx] * sc + sh;
  }
}

extern "C" void kernel_launch(void* const* d_in, const int* in_sizes, int n_in,
                              void* d_out, int out_size, void* d_ws, size_t ws_size,
                              hipStream_t stream) {
  const float* h     = (const float*)d_in[0];
  const int*   src   = (const int*)d_in[1];
  const int*   dst   = (const int*)d_in[2];
  const float* W     = (const float*)d_in[3];
  const float* bias  = (const float*)d_in[4];
  const float* gamma = (const float*)d_in[5];
  const float* beta  = (const float*)d_in[6];
  float* out = (float*)d_out;

  const int n = in_sizes[0] / FDIM;      // 50000
  const int E = in_sizes[1];             // 650000
  const int K = in_sizes[3] / FDIM;      // 1664

  char* base = (char*)d_ws;
  size_t off = 0;
  auto alloc = [&](size_t bytes) -> void* {
    void* p = base + off;
    off += (bytes + 255) & ~(size_t)255;
    return p;
  };
  int*   deg    = (int*)  alloc(4ull * n);
  int*   cursor = (int*)  alloc(4ull * n);
  float* bnsum  = (float*)alloc(512);
  float* bnsq   = (float*)alloc(512);
  const size_t zlen = off;               // zero deg+cursor+bn each call
  int*    offs  = (int*)  alloc(4ull * (n + 1));
  int*    bsums = (int*)  alloc(4ull * 256);
  int*    csr   = (int*)  alloc(4ull * E);
  float2* s12a  = (float2*)alloc(8ull * n);
  unsigned short* aggb = (unsigned short*)alloc(2ull * (size_t)n * 512);
  unsigned short* wBT  = (unsigned short*)alloc(2ull * (size_t)K * FDIM);
  unsigned short* hb   = (unsigned short*)alloc(2ull * (size_t)n * FDIM);
  (void)ws_size; (void)n_in; (void)out_size;

  const int eb = (E + 255) / 256;
  const int nb = (n + 255) / 256;
  const int w0 = n * FDIM / 8;           // conv_h work items
  const int w1 = K * FDIM;               // conv_wt work items
  const int w2 = E;                      // deg work items

  hipMemsetAsync(d_ws, 0, zlen, stream);
  prep_kernel<<<(w0 + w1 + w2 + 255) / 256, 256, 0, stream>>>(h, hb, W, wBT, dst, deg,
                                                              w0, w1, w2, K);
  scan1<<<nb, 256, 0, stream>>>(deg, offs, bsums, n);
  scan2<<<1, 256, 0, stream>>>(bsums, nb);
  scan3<<<nb, 256, 0, stream>>>(offs, bsums, n, E);
  csr_fill<<<eb, 256, 0, stream>>>(src, dst, offs, cursor, csr, E);
  agg_kernel<<<(n + 3) / 4, 256, 0, stream>>>(hb, csr, offs, aggb, s12a, n);
  const int gblocks = ((n + 127) / 128) * 2;
  gemm_kernel<<<gblocks, 256, 0, stream>>>(hb, wBT, aggb, s12a, bias,
                                           out, bnsum, bnsq, n, K);
  bn_norm<<<1024, 256, 0, stream>>>(out, bnsum, bnsq, gamma, beta, n);
}